// Round 8
// baseline (302.520 us; speedup 1.0000x reference)
//
#include <hip/hip_runtime.h>
#include <hip/hip_bf16.h>
#include <math.h>

#define NV 100000
#define NK 64
#define NF 16
#define EPS_W 1e-4f
#define ROWS_BYTES ((size_t)NV * 16 * 32)          // 51.2 MB bf16 rows
#define C4_BYTES   ((size_t)NV * 16)               // 1.6 MB padded coords
#define FB_BYTES   ((size_t)NV * 16 * 2)           // 3.2 MB bf16 feats
#define WS_NEED    ROWS_BYTES
#define WS_NEED2   (ROWS_BYTES + C4_BYTES + FB_BYTES)
#define GRID_MLP 3125                              // 12500 waves * 8 = 100000 vertices

typedef __attribute__((ext_vector_type(8))) short bf16x8;
typedef __attribute__((ext_vector_type(4))) float f32x4;

__device__ __forceinline__ unsigned short bfu(float x) {
    return __builtin_bit_cast(unsigned short, (__bf16)x);   // HW RNE cvt
}
__device__ __forceinline__ unsigned int pk2(float lo, float hi) {
    float2 t; t.x = lo; t.y = hi;
    __hip_bfloat162 r = __float22bfloat162_rn(t);           // v_cvt_pk_bf16_f32
    unsigned int u;
    __builtin_memcpy(&u, &r, 4);
    return u;
}
__device__ __forceinline__ float eluf(float x) {
    return x > 0.f ? x : __expf(x) - 1.f;
}

// ---------------------------------------------------------------------------
// prep2: coords -> float4 table (1.6MB, L2-resident) and feats -> bf16 table
// (3.2MB, L2-resident) so cov's random gathers stop re-fetching from HBM/L3.
// ---------------------------------------------------------------------------
__global__ void prep2_kernel(const float* __restrict__ coords,
                             const float* __restrict__ feats,
                             float4* __restrict__ c4,
                             unsigned short* __restrict__ fb) {
    int v = blockIdx.x * 256 + threadIdx.x;
    if (v < NV) {
        float4 r;
        r.x = coords[3 * v + 0];
        r.y = coords[3 * v + 1];
        r.z = coords[3 * v + 2];
        r.w = 0.f;
        c4[v] = r;
        const float* fp = feats + (size_t)v * 16;
        unsigned short* op = fb + (size_t)v * 16;
        #pragma unroll
        for (int i = 0; i < 16; ++i) op[i] = bfu(fp[i]);
    }
}

// ---------------------------------------------------------------------------
// Kernel A: neighbour covariance -> bf16 rows [v*16+f][16]
//   dims 0-8 cov, dim 9 = 1.0 (bias slot), rest 0
// MODE 0: raw coords + f32 feats.  MODE 2: c4 + bf16 feats (L2-resident).
// ---------------------------------------------------------------------------
template<int MODE>
__launch_bounds__(256)
__global__ void cov_kernel(const float* __restrict__ coords,
                           const float4* __restrict__ c4,
                           const unsigned short* __restrict__ fb,
                           const float* __restrict__ distsq,
                           const float* __restrict__ feats,
                           const int*   __restrict__ nidx,
                           unsigned char* __restrict__ ws)
{
    __shared__ float sEW[16][64];
    __shared__ int   sIX[16][64];
    const int tid = threadIdx.x;
    const int gv  = tid >> 4;          // vertex-in-block 0..15
    const int f   = tid & 15;          // feature 0..15
    const int v   = blockIdx.x * 16 + gv;

    {
        const size_t base = (size_t)v * NK + 4 * f;
        float4 d4 = *(const float4*)(distsq + base);
        int4   i4 = *(const int4*)(nidx + base);
        sEW[gv][4*f+0] = __expf(-10.f * d4.x);
        sEW[gv][4*f+1] = __expf(-10.f * d4.y);
        sEW[gv][4*f+2] = __expf(-10.f * d4.z);
        sEW[gv][4*f+3] = __expf(-10.f * d4.w);
        sIX[gv][4*f+0] = i4.x; sIX[gv][4*f+1] = i4.y;
        sIX[gv][4*f+2] = i4.z; sIX[gv][4*f+3] = i4.w;
    }
    __syncthreads();

    float s = 0.f, m0=0.f,m1=0.f,m2=0.f;
    float q00=0.f,q01=0.f,q02=0.f,q11=0.f,q12=0.f,q22=0.f;

    #pragma unroll 8
    for (int k = 0; k < NK; ++k) {
        int   idx = sIX[gv][k];
        float ew  = sEW[gv][k];
        float ft, x, y, z;
        if constexpr (MODE == 2) {
            unsigned int fu = fb[(size_t)idx * NF + f];
            ft = __builtin_bit_cast(float, fu << 16);
            float4 cd = c4[idx];
            x = cd.x; y = cd.y; z = cd.z;
        } else {
            ft = feats[(size_t)idx * NF + f];
            x = coords[(size_t)idx*3+0];
            y = coords[(size_t)idx*3+1];
            z = coords[(size_t)idx*3+2];
        }
        float w = ft * ew;
        s += w;
        m0 = fmaf(w,x,m0); m1 = fmaf(w,y,m1); m2 = fmaf(w,z,m2);
        float wx=w*x, wy=w*y, wz=w*z;
        q00=fmaf(wx,x,q00); q01=fmaf(wx,y,q01); q02=fmaf(wx,z,q02);
        q11=fmaf(wy,y,q11); q12=fmaf(wy,z,q12); q22=fmaf(wz,z,q22);
    }
    float inv = 1.f / (s + EPS_W);
    float mu0=m0*inv, mu1=m1*inv, mu2=m2*inv;
    float c00=fmaf(-mu0,mu0,q00*inv);
    float c01=fmaf(-mu0,mu1,q01*inv);
    float c02=fmaf(-mu0,mu2,q02*inv);
    float c11=fmaf(-mu1,mu1,q11*inv);
    float c12=fmaf(-mu1,mu2,q12*inv);
    float c22=fmaf(-mu2,mu2,q22*inv);

    uint4 lo, hi;
    lo.x = pk2(c00, c01);
    lo.y = pk2(c02, c01);
    lo.z = pk2(c11, c12);
    lo.w = pk2(c02, c12);
    hi.x = pk2(c22, 1.0f);
    hi.y = 0u; hi.z = 0u; hi.w = 0u;

    uint4* dst = (uint4*)(ws + ((size_t)v * 16 + f) * 32);
    dst[0] = lo;
    dst[1] = hi;
}

// ---------------------------------------------------------------------------
// Kernel B (mlp5): MFMA MLP, ONE vertex per wave-iteration (minimal live
// state -> unified VGPR<=128 via __launch_bounds__(256,4) -> 4 waves/SIMD),
// W1/W2 in swizzled LDS, biases in MFMA C-init, no explicit lgkm barriers
// (compiler inserts precise waits and can schedule across phases).
// D layout: col=lane&15, row=4*(lane>>4)+reg.  A/B: row/col=lane&15, k=8*(lane>>4)+i.
// ---------------------------------------------------------------------------
__device__ __forceinline__ bf16x8 rdfrag(const short* hb, int c, int g, int kc) {
    int boff = ((kc << 6) + (g << 4)) ^ ((c & 7) << 4);
    return *(const bf16x8*)(hb + c * 64 + (boff >> 1));
}
__device__ __forceinline__ void wrH(short* hb, int c, int g, int t,
                                    unsigned int p01, unsigned int p23) {
    int boff = ((t << 5) + (g << 3)) ^ ((c & 7) << 4);
    uint2 val; val.x = p01; val.y = p23;
    *(uint2*)(hb + c * 64 + (boff >> 1)) = val;
}
__device__ __forceinline__ bf16x8 rdW(const short* sw, int c, int g, int t, int kc) {
    int byte = (t << 11) + (c << 7) + (kc << 6) + (g << 4);
    byte ^= (c & 7) << 4;
    return *(const bf16x8*)((const char*)sw + byte);
}

__launch_bounds__(256, 4)
__global__ void mlp5_kernel(const unsigned char* __restrict__ ws,
                            const float* __restrict__ W0, const float* __restrict__ b0,
                            const float* __restrict__ W1, const float* __restrict__ b1,
                            const float* __restrict__ W2, const float* __restrict__ b2,
                            const float* __restrict__ W3, const float* __restrict__ b3,
                            float* __restrict__ out)
{
    __shared__ __align__(16) short sW1[4096];          // 8 KB swizzled W1^T
    __shared__ __align__(16) short sW2[4096];          // 8 KB swizzled W2^T
    __shared__ __align__(16) short hbuf[4][1024];      // 8 KB -> total 24 KB

    const int tid  = threadIdx.x;
    const int wid  = tid >> 6;
    const int lane = tid & 63;
    const int c    = lane & 15;
    const int g    = lane >> 4;

    union U8 { short s[8]; bf16x8 v; };

    // ---- stage W1,W2 into swizzled LDS ----
    #pragma unroll
    for (int r = 0; r < 2; ++r) {
        int t = tid + r * 256;          // task: j = t&63, k-oct o = t>>6
        int j = t & 63, o = t >> 6;
        U8 u1, u2;
        #pragma unroll
        for (int i = 0; i < 8; ++i) {
            u1.s[i] = (short)bfu(W1[(8 * o + i) * 64 + j]);
            u2.s[i] = (short)bfu(W2[(8 * o + i) * 64 + j]);
        }
        int byte = ((j << 7) + (o << 4)) ^ ((j & 7) << 4);
        *(bf16x8*)((char*)sW1 + byte) = u1.v;
        *(bf16x8*)((char*)sW2 + byte) = u2.v;
    }
    __syncthreads();

    // ---- W0 / W3 fragments + biases in VGPRs ----
    bf16x8 w0f[4], w3f[2];
    #pragma unroll
    for (int t = 0; t < 4; ++t) {
        U8 u;
        #pragma unroll
        for (int i = 0; i < 8; ++i) {
            int k = 8 * g + i;
            float val = 0.f;
            if (k < 9)       val = W0[k * 64 + 16 * t + c];
            else if (k == 9) val = b0[16 * t + c];       // bias via dim-9 = 1.0
            u.s[i] = (short)bfu(val);
        }
        w0f[t] = u.v;
    }
    #pragma unroll
    for (int kc = 0; kc < 2; ++kc) {
        U8 u;
        #pragma unroll
        for (int i = 0; i < 8; ++i) {
            int k = 32 * kc + 8 * g + i;
            u.s[i] = (short)bfu(c < 9 ? W3[k * 9 + c] : 0.f);
        }
        w3f[kc] = u.v;
    }
    float b1v[16], b2v[16], b3v[4];
    #pragma unroll
    for (int t = 0; t < 4; ++t)
        #pragma unroll
        for (int r = 0; r < 4; ++r) {
            b1v[4 * t + r] = b1[16 * t + 4 * g + r];
            b2v[4 * t + r] = b2[16 * t + 4 * g + r];
        }
    #pragma unroll
    for (int r = 0; r < 4; ++r)
        b3v[r] = (4 * g + r < 9) ? b3[4 * g + r] : 0.f;

    short* hb = &hbuf[wid][0];

    // ---- vertex loop with row prefetch ----
    const int stride = gridDim.x * 4;
    int v = blockIdx.x * 4 + wid;
    if (v >= NV) return;

    const unsigned char* wp = ws + (size_t)v * 512 + (c << 5) + ((g & 1) << 4);
    const size_t wstep = (size_t)stride * 512;
    float* op = out + (size_t)v * 144 + 9 * c + (g << 2);
    const size_t ostep = (size_t)stride * 144;

    bf16x8 bin = *(const bf16x8*)(wp);

    for (; v < NV; v += stride) {
        const unsigned char* wpn = (v + stride < NV) ? (wp + wstep) : wp;
        bf16x8 nb = *(const bf16x8*)(wpn);

        f32x4 A[4];

        // ---- layer 0 (bias via k=9 slot; C = 0) ----
        #pragma unroll
        for (int t = 0; t < 4; ++t) {
            f32x4 z4 = {0.f, 0.f, 0.f, 0.f};
            A[t] = __builtin_amdgcn_mfma_f32_16x16x32_bf16(w0f[t], bin, z4, 0, 0, 0);
        }
        #pragma unroll
        for (int t = 0; t < 4; ++t)
            wrH(hb, c, g, t, pk2(eluf(A[t][0]), eluf(A[t][1])),
                             pk2(eluf(A[t][2]), eluf(A[t][3])));

        // ---- layer 1 (C = b1) ----
        {
            bf16x8 h0 = rdfrag(hb, c, g, 0), h1 = rdfrag(hb, c, g, 1);
            #pragma unroll
            for (int t = 0; t < 4; ++t) {
                bf16x8 wa = rdW(sW1, c, g, t, 0);
                bf16x8 wb = rdW(sW1, c, g, t, 1);
                f32x4 a = { b1v[4*t+0], b1v[4*t+1], b1v[4*t+2], b1v[4*t+3] };
                a = __builtin_amdgcn_mfma_f32_16x16x32_bf16(wa, h0, a, 0, 0, 0);
                a = __builtin_amdgcn_mfma_f32_16x16x32_bf16(wb, h1, a, 0, 0, 0);
                A[t] = a;
            }
            #pragma unroll
            for (int t = 0; t < 4; ++t)
                wrH(hb, c, g, t, pk2(eluf(A[t][0]), eluf(A[t][1])),
                                 pk2(eluf(A[t][2]), eluf(A[t][3])));
        }

        // ---- layer 2 (C = b2) ----
        {
            bf16x8 h0 = rdfrag(hb, c, g, 0), h1 = rdfrag(hb, c, g, 1);
            #pragma unroll
            for (int t = 0; t < 4; ++t) {
                bf16x8 wa = rdW(sW2, c, g, t, 0);
                bf16x8 wb = rdW(sW2, c, g, t, 1);
                f32x4 a = { b2v[4*t+0], b2v[4*t+1], b2v[4*t+2], b2v[4*t+3] };
                a = __builtin_amdgcn_mfma_f32_16x16x32_bf16(wa, h0, a, 0, 0, 0);
                a = __builtin_amdgcn_mfma_f32_16x16x32_bf16(wb, h1, a, 0, 0, 0);
                A[t] = a;
            }
            #pragma unroll
            for (int t = 0; t < 4; ++t)
                wrH(hb, c, g, t, pk2(eluf(A[t][0]), eluf(A[t][1])),
                                 pk2(eluf(A[t][2]), eluf(A[t][3])));
        }

        // ---- layer 3: 64 -> 9 (C = b3) ----
        {
            bf16x8 h0 = rdfrag(hb, c, g, 0), h1 = rdfrag(hb, c, g, 1);
            f32x4 a = { b3v[0], b3v[1], b3v[2], b3v[3] };
            a = __builtin_amdgcn_mfma_f32_16x16x32_bf16(w3f[0], h0, a, 0, 0, 0);
            a = __builtin_amdgcn_mfma_f32_16x16x32_bf16(w3f[1], h1, a, 0, 0, 0);
            if (g < 2) {
                op[0] = eluf(a[0]); op[1] = eluf(a[1]);
                op[2] = eluf(a[2]); op[3] = eluf(a[3]);
            } else if (g == 2) {
                op[0] = eluf(a[0]);   // dim 8
            }
        }

        bin = nb;
        wp = wpn;
        op += ostep;
    }
}

// ---------------------------------------------------------------------------
// Fallback: round-1 fp32 fused kernel (only if ws too small)
// ---------------------------------------------------------------------------
__launch_bounds__(256, 2)
__global__ void fused_pca_mlp(const float* __restrict__ coords,
                              const float* __restrict__ distsq,
                              const float* __restrict__ feats,
                              const int*   __restrict__ nidx,
                              const float* __restrict__ W0, const float* __restrict__ b0,
                              const float* __restrict__ W1, const float* __restrict__ b1,
                              const float* __restrict__ W2, const float* __restrict__ b2,
                              const float* __restrict__ W3, const float* __restrict__ b3,
                              float* __restrict__ out)
{
    __shared__ __align__(16) float sW0t[64 * 9];
    __shared__ __align__(16) float sW1t[64 * 64];
    __shared__ __align__(16) float sW2t[64 * 64];
    __shared__ __align__(16) float sW3t[9 * 64];
    __shared__ float sB0[64], sB1[64], sB2[64], sB3[9];
    const int tid = threadIdx.x;
    for (int t = tid; t < 64 * 9; t += 256) { int j = t / 9, i = t - j * 9; sW0t[t] = W0[i * 64 + j]; }
    for (int t = tid; t < 64 * 64; t += 256) { int j = t >> 6, i = t & 63; sW1t[t] = W1[i * 64 + j]; }
    for (int t = tid; t < 64 * 64; t += 256) { int j = t >> 6, i = t & 63; sW2t[t] = W2[i * 64 + j]; }
    for (int t = tid; t < 9 * 64; t += 256) { int j = t >> 6, i = t & 63; sW3t[t] = W3[i * 9 + j]; }
    if (tid < 64) { sB0[tid] = b0[tid]; sB1[tid] = b1[tid]; sB2[tid] = b2[tid]; }
    if (tid < 9)  { sB3[tid] = b3[tid]; }
    __syncthreads();
    const int g = tid >> 4, f = tid & 15;
    const int v = blockIdx.x * 16 + g;
    if (v >= NV) return;
    const int* nix = nidx + (size_t)v * NK;
    const float* dsq = distsq + (size_t)v * NK;
    float s = 0.f, m0=0,m1=0,m2=0, q00=0,q01=0,q02=0,q11=0,q12=0,q22=0;
    #pragma unroll 4
    for (int k = 0; k < NK; ++k) {
        int idx = nix[k];
        float ew = __expf(-10.0f * dsq[k]);
        float w = feats[(size_t)idx * NF + f] * ew;
        float x = coords[(size_t)idx*3+0], y = coords[(size_t)idx*3+1], z = coords[(size_t)idx*3+2];
        s += w; m0 = fmaf(w,x,m0); m1 = fmaf(w,y,m1); m2 = fmaf(w,z,m2);
        float wx=w*x, wy=w*y, wz=w*z;
        q00=fmaf(wx,x,q00); q01=fmaf(wx,y,q01); q02=fmaf(wx,z,q02);
        q11=fmaf(wy,y,q11); q12=fmaf(wy,z,q12); q22=fmaf(wz,z,q22);
    }
    float inv = 1.0f/(s+EPS_W), mu0=m0*inv, mu1=m1*inv, mu2=m2*inv;
    float xr[9];
    xr[0]=fmaf(-mu0,mu0,q00*inv); xr[1]=fmaf(-mu0,mu1,q01*inv); xr[2]=fmaf(-mu0,mu2,q02*inv);
    xr[3]=xr[1]; xr[4]=fmaf(-mu1,mu1,q11*inv); xr[5]=fmaf(-mu1,mu2,q12*inv);
    xr[6]=xr[2]; xr[7]=xr[5]; xr[8]=fmaf(-mu2,mu2,q22*inv);
    float h[64], gg[64];
    #pragma unroll
    for (int j = 0; j < 64; ++j) {
        float aa = sB0[j]; const float* wr = sW0t + j * 9;
        #pragma unroll
        for (int i = 0; i < 9; ++i) aa = fmaf(xr[i], wr[i], aa);
        h[j] = eluf(aa);
    }
    #pragma unroll
    for (int j = 0; j < 64; ++j) {
        float aa = sB1[j]; const float4* wr = (const float4*)(sW1t + (j << 6));
        #pragma unroll
        for (int i4 = 0; i4 < 16; ++i4) { float4 wv = wr[i4];
            aa = fmaf(h[4*i4+0],wv.x,aa); aa = fmaf(h[4*i4+1],wv.y,aa);
            aa = fmaf(h[4*i4+2],wv.z,aa); aa = fmaf(h[4*i4+3],wv.w,aa); }
        gg[j] = eluf(aa);
    }
    #pragma unroll
    for (int j = 0; j < 64; ++j) {
        float aa = sB2[j]; const float4* wr = (const float4*)(sW2t + (j << 6));
        #pragma unroll
        for (int i4 = 0; i4 < 16; ++i4) { float4 wv = wr[i4];
            aa = fmaf(gg[4*i4+0],wv.x,aa); aa = fmaf(gg[4*i4+1],wv.y,aa);
            aa = fmaf(gg[4*i4+2],wv.z,aa); aa = fmaf(gg[4*i4+3],wv.w,aa); }
        h[j] = eluf(aa);
    }
    float o[9];
    #pragma unroll
    for (int j = 0; j < 9; ++j) {
        float aa = sB3[j]; const float4* wr = (const float4*)(sW3t + (j << 6));
        #pragma unroll
        for (int i4 = 0; i4 < 16; ++i4) { float4 wv = wr[i4];
            aa = fmaf(h[4*i4+0],wv.x,aa); aa = fmaf(h[4*i4+1],wv.y,aa);
            aa = fmaf(h[4*i4+2],wv.z,aa); aa = fmaf(h[4*i4+3],wv.w,aa); }
        o[j] = eluf(aa);
    }
    float* op = out + ((size_t)v * NF + f) * 9;
    #pragma unroll
    for (int j = 0; j < 9; ++j) op[j] = o[j];
}

extern "C" void kernel_launch(void* const* d_in, const int* in_sizes, int n_in,
                              void* d_out, int out_size, void* d_ws, size_t ws_size,
                              hipStream_t stream) {
    (void)in_sizes; (void)n_in; (void)out_size;
    const float* coords = (const float*)d_in[0];
    const float* distsq = (const float*)d_in[1];
    const float* feats  = (const float*)d_in[2];
    const int*   nidx   = (const int*)d_in[3];
    const float* W0 = (const float*)d_in[4];
    const float* b0 = (const float*)d_in[5];
    const float* W1 = (const float*)d_in[6];
    const float* b1 = (const float*)d_in[7];
    const float* W2 = (const float*)d_in[8];
    const float* b2 = (const float*)d_in[9];
    const float* W3 = (const float*)d_in[10];
    const float* b3 = (const float*)d_in[11];
    float* out = (float*)d_out;

    if (ws_size >= WS_NEED2) {
        unsigned char* ws = (unsigned char*)d_ws;
        float4* c4 = (float4*)(ws + ROWS_BYTES);
        unsigned short* fb = (unsigned short*)(ws + ROWS_BYTES + C4_BYTES);
        hipLaunchKernelGGL(prep2_kernel, dim3((NV + 255) / 256), dim3(256), 0, stream,
                           coords, feats, c4, fb);
        hipLaunchKernelGGL((cov_kernel<2>), dim3(NV / 16), dim3(256), 0, stream,
                           coords, c4, fb, distsq, feats, nidx, ws);
        hipLaunchKernelGGL(mlp5_kernel, dim3(GRID_MLP), dim3(256), 0, stream,
                           ws, W0, b0, W1, b1, W2, b2, W3, b3, out);
    } else if (ws_size >= WS_NEED) {
        unsigned char* ws = (unsigned char*)d_ws;
        hipLaunchKernelGGL((cov_kernel<0>), dim3(NV / 16), dim3(256), 0, stream,
                           coords, (const float4*)nullptr, (const unsigned short*)nullptr,
                           distsq, feats, nidx, ws);
        hipLaunchKernelGGL(mlp5_kernel, dim3(GRID_MLP), dim3(256), 0, stream,
                           ws, W0, b0, W1, b1, W2, b2, W3, b3, out);
    } else {
        hipLaunchKernelGGL(fused_pca_mlp, dim3(NV / 16), dim3(256), 0, stream,
                           coords, distsq, feats, nidx,
                           W0, b0, W1, b1, W2, b2, W3, b3, out);
    }
}

// Round 9
// 201.348 us; speedup vs baseline: 1.5025x; 1.5025x over previous
//
#include <hip/hip_runtime.h>
#include <hip/hip_bf16.h>
#include <math.h>

#define NV 100000
#define NK 64
#define NF 16
#define EPS_W 1e-4f
#define WS_NEED ((size_t)NV * 16 * 32)   // 51.2 MB bf16 rows
#define GRID_MLP 3125                    // 12500 waves * 8 = 100000 vertices

typedef __attribute__((ext_vector_type(8))) short bf16x8;
typedef __attribute__((ext_vector_type(4))) float f32x4;

__device__ __forceinline__ unsigned short bfu(float x) {
    return __builtin_bit_cast(unsigned short, (__bf16)x);   // HW RNE cvt
}
__device__ __forceinline__ unsigned int pk2(float lo, float hi) {
    float2 t; t.x = lo; t.y = hi;
    __hip_bfloat162 r = __float22bfloat162_rn(t);           // v_cvt_pk_bf16_f32
    unsigned int u;
    __builtin_memcpy(&u, &r, 4);
    return u;
}
__device__ __forceinline__ float eluf(float x) {
    return x > 0.f ? x : __expf(x) - 1.f;
}

// ---------------------------------------------------------------------------
// Kernel A: neighbour covariance (round-2 structure, known ~81us)
// writes bf16 rows [v*16+f][16]: dims 0-8 cov, dim 9 = 1.0 (bias slot), rest 0
// ---------------------------------------------------------------------------
__launch_bounds__(256)
__global__ void cov_kernel(const float* __restrict__ coords,
                           const float* __restrict__ distsq,
                           const float* __restrict__ feats,
                           const int*   __restrict__ nidx,
                           unsigned char* __restrict__ ws)
{
    __shared__ float sEW[16][64];
    __shared__ int   sIX[16][64];
    const int tid = threadIdx.x;
    const int gv  = tid >> 4;          // vertex-in-block 0..15
    const int f   = tid & 15;          // feature 0..15
    const int v   = blockIdx.x * 16 + gv;

    {
        const size_t base = (size_t)v * NK + 4 * f;
        float4 d4 = *(const float4*)(distsq + base);
        int4   i4 = *(const int4*)(nidx + base);
        sEW[gv][4*f+0] = __expf(-10.f * d4.x);
        sEW[gv][4*f+1] = __expf(-10.f * d4.y);
        sEW[gv][4*f+2] = __expf(-10.f * d4.z);
        sEW[gv][4*f+3] = __expf(-10.f * d4.w);
        sIX[gv][4*f+0] = i4.x; sIX[gv][4*f+1] = i4.y;
        sIX[gv][4*f+2] = i4.z; sIX[gv][4*f+3] = i4.w;
    }
    __syncthreads();

    float s = 0.f, m0=0.f,m1=0.f,m2=0.f;
    float q00=0.f,q01=0.f,q02=0.f,q11=0.f,q12=0.f,q22=0.f;

    #pragma unroll 8
    for (int k = 0; k < NK; ++k) {
        int   idx = sIX[gv][k];
        float ew  = sEW[gv][k];
        float w   = feats[(size_t)idx * NF + f] * ew;
        float x = coords[(size_t)idx*3+0];
        float y = coords[(size_t)idx*3+1];
        float z = coords[(size_t)idx*3+2];
        s += w;
        m0 = fmaf(w,x,m0); m1 = fmaf(w,y,m1); m2 = fmaf(w,z,m2);
        float wx=w*x, wy=w*y, wz=w*z;
        q00=fmaf(wx,x,q00); q01=fmaf(wx,y,q01); q02=fmaf(wx,z,q02);
        q11=fmaf(wy,y,q11); q12=fmaf(wy,z,q12); q22=fmaf(wz,z,q22);
    }
    float inv = 1.f / (s + EPS_W);
    float mu0=m0*inv, mu1=m1*inv, mu2=m2*inv;
    float c00=fmaf(-mu0,mu0,q00*inv);
    float c01=fmaf(-mu0,mu1,q01*inv);
    float c02=fmaf(-mu0,mu2,q02*inv);
    float c11=fmaf(-mu1,mu1,q11*inv);
    float c12=fmaf(-mu1,mu2,q12*inv);
    float c22=fmaf(-mu2,mu2,q22*inv);

    uint4 lo, hi;
    lo.x = pk2(c00, c01);
    lo.y = pk2(c02, c01);
    lo.z = pk2(c11, c12);
    lo.w = pk2(c02, c12);
    hi.x = pk2(c22, 1.0f);
    hi.y = 0u; hi.z = 0u; hi.w = 0u;

    uint4* dst = (uint4*)(ws + ((size_t)v * 16 + f) * 32);
    dst[0] = lo;
    dst[1] = hi;
}

// ---------------------------------------------------------------------------
// Kernel B (mlp5b): MFMA MLP, 1 vertex/wave-iter, 24KB LDS (6 blocks/CU),
// biases in MFMA C-init, cvt_pk packing, row prefetch, and a FULL-SECTOR
// epilogue: 144 output floats staged in (dead) hbuf, stored as 36 aligned
// contiguous float4 lanes -> 9 complete 64B sectors, no partial-write RMW.
// D layout: col=lane&15, row=4*(lane>>4)+reg.  A/B: row/col=lane&15, k=8*(lane>>4)+i.
// ---------------------------------------------------------------------------
__device__ __forceinline__ bf16x8 rdfrag(const short* hb, int c, int g, int kc) {
    int boff = ((kc << 6) + (g << 4)) ^ ((c & 7) << 4);
    return *(const bf16x8*)(hb + c * 64 + (boff >> 1));
}
__device__ __forceinline__ void wrH(short* hb, int c, int g, int t,
                                    unsigned int p01, unsigned int p23) {
    int boff = ((t << 5) + (g << 3)) ^ ((c & 7) << 4);
    uint2 val; val.x = p01; val.y = p23;
    *(uint2*)(hb + c * 64 + (boff >> 1)) = val;
}
__device__ __forceinline__ bf16x8 rdW(const short* sw, int c, int g, int t, int kc) {
    int byte = (t << 11) + (c << 7) + (kc << 6) + (g << 4);
    byte ^= (c & 7) << 4;
    return *(const bf16x8*)((const char*)sw + byte);
}

__launch_bounds__(256, 4)
__global__ void mlp5b_kernel(const unsigned char* __restrict__ ws,
                             const float* __restrict__ W0, const float* __restrict__ b0,
                             const float* __restrict__ W1, const float* __restrict__ b1,
                             const float* __restrict__ W2, const float* __restrict__ b2,
                             const float* __restrict__ W3, const float* __restrict__ b3,
                             float* __restrict__ out)
{
    __shared__ __align__(16) short sW1[4096];          // 8 KB swizzled W1^T
    __shared__ __align__(16) short sW2[4096];          // 8 KB swizzled W2^T
    __shared__ __align__(16) short hbuf[4][1024];      // 8 KB -> total 24 KB

    const int tid  = threadIdx.x;
    const int wid  = tid >> 6;
    const int lane = tid & 63;
    const int c    = lane & 15;
    const int g    = lane >> 4;

    union U8 { short s[8]; bf16x8 v; };

    // ---- stage W1,W2 into swizzled LDS ----
    #pragma unroll
    for (int r = 0; r < 2; ++r) {
        int t = tid + r * 256;          // task: j = t&63, k-oct o = t>>6
        int j = t & 63, o = t >> 6;
        U8 u1, u2;
        #pragma unroll
        for (int i = 0; i < 8; ++i) {
            u1.s[i] = (short)bfu(W1[(8 * o + i) * 64 + j]);
            u2.s[i] = (short)bfu(W2[(8 * o + i) * 64 + j]);
        }
        int byte = ((j << 7) + (o << 4)) ^ ((j & 7) << 4);
        *(bf16x8*)((char*)sW1 + byte) = u1.v;
        *(bf16x8*)((char*)sW2 + byte) = u2.v;
    }
    __syncthreads();

    // ---- W0 / W3 fragments + biases in VGPRs ----
    bf16x8 w0f[4], w3f[2];
    #pragma unroll
    for (int t = 0; t < 4; ++t) {
        U8 u;
        #pragma unroll
        for (int i = 0; i < 8; ++i) {
            int k = 8 * g + i;
            float val = 0.f;
            if (k < 9)       val = W0[k * 64 + 16 * t + c];
            else if (k == 9) val = b0[16 * t + c];       // bias via dim-9 = 1.0
            u.s[i] = (short)bfu(val);
        }
        w0f[t] = u.v;
    }
    #pragma unroll
    for (int kc = 0; kc < 2; ++kc) {
        U8 u;
        #pragma unroll
        for (int i = 0; i < 8; ++i) {
            int k = 32 * kc + 8 * g + i;
            u.s[i] = (short)bfu(c < 9 ? W3[k * 9 + c] : 0.f);
        }
        w3f[kc] = u.v;
    }
    float b1v[16], b2v[16], b3v[4];
    #pragma unroll
    for (int t = 0; t < 4; ++t)
        #pragma unroll
        for (int r = 0; r < 4; ++r) {
            b1v[4 * t + r] = b1[16 * t + 4 * g + r];
            b2v[4 * t + r] = b2[16 * t + 4 * g + r];
        }
    #pragma unroll
    for (int r = 0; r < 4; ++r)
        b3v[r] = (4 * g + r < 9) ? b3[4 * g + r] : 0.f;

    short* hb = &hbuf[wid][0];
    float* fOut = (float*)hb;      // hbuf is dead during the epilogue

    // ---- vertex loop with row prefetch ----
    const int stride = gridDim.x * 4;
    int v = blockIdx.x * 4 + wid;
    if (v >= NV) return;

    const unsigned char* wp = ws + (size_t)v * 512 + (c << 5) + ((g & 1) << 4);
    const size_t wstep = (size_t)stride * 512;
    float* ob = out + (size_t)v * 144;
    const size_t ostep = (size_t)stride * 144;

    bf16x8 bin = *(const bf16x8*)(wp);

    for (; v < NV; v += stride) {
        const unsigned char* wpn = (v + stride < NV) ? (wp + wstep) : wp;
        bf16x8 nb = *(const bf16x8*)(wpn);

        f32x4 A[4];

        // ---- layer 0 (bias via k=9 slot; C = 0) ----
        #pragma unroll
        for (int t = 0; t < 4; ++t) {
            f32x4 z4 = {0.f, 0.f, 0.f, 0.f};
            A[t] = __builtin_amdgcn_mfma_f32_16x16x32_bf16(w0f[t], bin, z4, 0, 0, 0);
        }
        #pragma unroll
        for (int t = 0; t < 4; ++t)
            wrH(hb, c, g, t, pk2(eluf(A[t][0]), eluf(A[t][1])),
                             pk2(eluf(A[t][2]), eluf(A[t][3])));
        __asm__ volatile("s_waitcnt lgkmcnt(0)" ::: "memory");

        // ---- layer 1 (C = b1) ----
        {
            bf16x8 h0 = rdfrag(hb, c, g, 0), h1 = rdfrag(hb, c, g, 1);
            #pragma unroll
            for (int t = 0; t < 4; ++t) {
                bf16x8 wa = rdW(sW1, c, g, t, 0);
                bf16x8 wb = rdW(sW1, c, g, t, 1);
                f32x4 a = { b1v[4*t+0], b1v[4*t+1], b1v[4*t+2], b1v[4*t+3] };
                a = __builtin_amdgcn_mfma_f32_16x16x32_bf16(wa, h0, a, 0, 0, 0);
                a = __builtin_amdgcn_mfma_f32_16x16x32_bf16(wb, h1, a, 0, 0, 0);
                A[t] = a;
            }
            #pragma unroll
            for (int t = 0; t < 4; ++t)
                wrH(hb, c, g, t, pk2(eluf(A[t][0]), eluf(A[t][1])),
                                 pk2(eluf(A[t][2]), eluf(A[t][3])));
        }
        __asm__ volatile("s_waitcnt lgkmcnt(0)" ::: "memory");

        // ---- layer 2 (C = b2) ----
        {
            bf16x8 h0 = rdfrag(hb, c, g, 0), h1 = rdfrag(hb, c, g, 1);
            #pragma unroll
            for (int t = 0; t < 4; ++t) {
                bf16x8 wa = rdW(sW2, c, g, t, 0);
                bf16x8 wb = rdW(sW2, c, g, t, 1);
                f32x4 a = { b2v[4*t+0], b2v[4*t+1], b2v[4*t+2], b2v[4*t+3] };
                a = __builtin_amdgcn_mfma_f32_16x16x32_bf16(wa, h0, a, 0, 0, 0);
                a = __builtin_amdgcn_mfma_f32_16x16x32_bf16(wb, h1, a, 0, 0, 0);
                A[t] = a;
            }
            #pragma unroll
            for (int t = 0; t < 4; ++t)
                wrH(hb, c, g, t, pk2(eluf(A[t][0]), eluf(A[t][1])),
                                 pk2(eluf(A[t][2]), eluf(A[t][3])));
        }
        __asm__ volatile("s_waitcnt lgkmcnt(0)" ::: "memory");

        // ---- layer 3: 64 -> 9 (C = b3), stage to LDS ----
        {
            bf16x8 h0 = rdfrag(hb, c, g, 0), h1 = rdfrag(hb, c, g, 1);
            f32x4 a = { b3v[0], b3v[1], b3v[2], b3v[3] };
            a = __builtin_amdgcn_mfma_f32_16x16x32_bf16(w3f[0], h0, a, 0, 0, 0);
            a = __builtin_amdgcn_mfma_f32_16x16x32_bf16(w3f[1], h1, a, 0, 0, 0);
            // lane(c,g) reg j holds out-dim d=4g+j of feature c
            if (g < 2) {
                fOut[c * 9 + 4 * g + 0] = eluf(a[0]);
                fOut[c * 9 + 4 * g + 1] = eluf(a[1]);
                fOut[c * 9 + 4 * g + 2] = eluf(a[2]);
                fOut[c * 9 + 4 * g + 3] = eluf(a[3]);
            } else if (g == 2) {
                fOut[c * 9 + 8] = eluf(a[0]);
            }
        }
        __asm__ volatile("s_waitcnt lgkmcnt(0)" ::: "memory");

        // ---- full-sector store: 36 lanes x contiguous float4 = 576B ----
        if (lane < 36) {
            float4 val = *(const float4*)(fOut + lane * 4);
            *(float4*)(ob + lane * 4) = val;
        }
        __asm__ volatile("s_waitcnt lgkmcnt(0)" ::: "memory");  // fOut reads done before next wrH

        bin = nb;
        wp = wpn;
        ob += ostep;
    }
}

// ---------------------------------------------------------------------------
// Fallback: round-1 fp32 fused kernel (only if ws too small)
// ---------------------------------------------------------------------------
__launch_bounds__(256, 2)
__global__ void fused_pca_mlp(const float* __restrict__ coords,
                              const float* __restrict__ distsq,
                              const float* __restrict__ feats,
                              const int*   __restrict__ nidx,
                              const float* __restrict__ W0, const float* __restrict__ b0,
                              const float* __restrict__ W1, const float* __restrict__ b1,
                              const float* __restrict__ W2, const float* __restrict__ b2,
                              const float* __restrict__ W3, const float* __restrict__ b3,
                              float* __restrict__ out)
{
    __shared__ __align__(16) float sW0t[64 * 9];
    __shared__ __align__(16) float sW1t[64 * 64];
    __shared__ __align__(16) float sW2t[64 * 64];
    __shared__ __align__(16) float sW3t[9 * 64];
    __shared__ float sB0[64], sB1[64], sB2[64], sB3[9];
    const int tid = threadIdx.x;
    for (int t = tid; t < 64 * 9; t += 256) { int j = t / 9, i = t - j * 9; sW0t[t] = W0[i * 64 + j]; }
    for (int t = tid; t < 64 * 64; t += 256) { int j = t >> 6, i = t & 63; sW1t[t] = W1[i * 64 + j]; }
    for (int t = tid; t < 64 * 64; t += 256) { int j = t >> 6, i = t & 63; sW2t[t] = W2[i * 64 + j]; }
    for (int t = tid; t < 9 * 64; t += 256) { int j = t >> 6, i = t & 63; sW3t[t] = W3[i * 9 + j]; }
    if (tid < 64) { sB0[tid] = b0[tid]; sB1[tid] = b1[tid]; sB2[tid] = b2[tid]; }
    if (tid < 9)  { sB3[tid] = b3[tid]; }
    __syncthreads();
    const int g = tid >> 4, f = tid & 15;
    const int v = blockIdx.x * 16 + g;
    if (v >= NV) return;
    const int* nix = nidx + (size_t)v * NK;
    const float* dsq = distsq + (size_t)v * NK;
    float s = 0.f, m0=0,m1=0,m2=0, q00=0,q01=0,q02=0,q11=0,q12=0,q22=0;
    #pragma unroll 4
    for (int k = 0; k < NK; ++k) {
        int idx = nix[k];
        float ew = __expf(-10.0f * dsq[k]);
        float w = feats[(size_t)idx * NF + f] * ew;
        float x = coords[(size_t)idx*3+0], y = coords[(size_t)idx*3+1], z = coords[(size_t)idx*3+2];
        s += w; m0 = fmaf(w,x,m0); m1 = fmaf(w,y,m1); m2 = fmaf(w,z,m2);
        float wx=w*x, wy=w*y, wz=w*z;
        q00=fmaf(wx,x,q00); q01=fmaf(wx,y,q01); q02=fmaf(wx,z,q02);
        q11=fmaf(wy,y,q11); q12=fmaf(wy,z,q12); q22=fmaf(wz,z,q22);
    }
    float inv = 1.0f/(s+EPS_W), mu0=m0*inv, mu1=m1*inv, mu2=m2*inv;
    float xr[9];
    xr[0]=fmaf(-mu0,mu0,q00*inv); xr[1]=fmaf(-mu0,mu1,q01*inv); xr[2]=fmaf(-mu0,mu2,q02*inv);
    xr[3]=xr[1]; xr[4]=fmaf(-mu1,mu1,q11*inv); xr[5]=fmaf(-mu1,mu2,q12*inv);
    xr[6]=xr[2]; xr[7]=xr[5]; xr[8]=fmaf(-mu2,mu2,q22*inv);
    float h[64], gg[64];
    #pragma unroll
    for (int j = 0; j < 64; ++j) {
        float aa = sB0[j]; const float* wr = sW0t + j * 9;
        #pragma unroll
        for (int i = 0; i < 9; ++i) aa = fmaf(xr[i], wr[i], aa);
        h[j] = eluf(aa);
    }
    #pragma unroll
    for (int j = 0; j < 64; ++j) {
        float aa = sB1[j]; const float4* wr = (const float4*)(sW1t + (j << 6));
        #pragma unroll
        for (int i4 = 0; i4 < 16; ++i4) { float4 wv = wr[i4];
            aa = fmaf(h[4*i4+0],wv.x,aa); aa = fmaf(h[4*i4+1],wv.y,aa);
            aa = fmaf(h[4*i4+2],wv.z,aa); aa = fmaf(h[4*i4+3],wv.w,aa); }
        gg[j] = eluf(aa);
    }
    #pragma unroll
    for (int j = 0; j < 64; ++j) {
        float aa = sB2[j]; const float4* wr = (const float4*)(sW2t + (j << 6));
        #pragma unroll
        for (int i4 = 0; i4 < 16; ++i4) { float4 wv = wr[i4];
            aa = fmaf(gg[4*i4+0],wv.x,aa); aa = fmaf(gg[4*i4+1],wv.y,aa);
            aa = fmaf(gg[4*i4+2],wv.z,aa); aa = fmaf(gg[4*i4+3],wv.w,aa); }
        h[j] = eluf(aa);
    }
    float o[9];
    #pragma unroll
    for (int j = 0; j < 9; ++j) {
        float aa = sB3[j]; const float4* wr = (const float4*)(sW3t + (j << 6));
        #pragma unroll
        for (int i4 = 0; i4 < 16; ++i4) { float4 wv = wr[i4];
            aa = fmaf(h[4*i4+0],wv.x,aa); aa = fmaf(h[4*i4+1],wv.y,aa);
            aa = fmaf(h[4*i4+2],wv.z,aa); aa = fmaf(h[4*i4+3],wv.w,aa); }
        o[j] = eluf(aa);
    }
    float* op = out + ((size_t)v * NF + f) * 9;
    #pragma unroll
    for (int j = 0; j < 9; ++j) op[j] = o[j];
}

extern "C" void kernel_launch(void* const* d_in, const int* in_sizes, int n_in,
                              void* d_out, int out_size, void* d_ws, size_t ws_size,
                              hipStream_t stream) {
    (void)in_sizes; (void)n_in; (void)out_size;
    const float* coords = (const float*)d_in[0];
    const float* distsq = (const float*)d_in[1];
    const float* feats  = (const float*)d_in[2];
    const int*   nidx   = (const int*)d_in[3];
    const float* W0 = (const float*)d_in[4];
    const float* b0 = (const float*)d_in[5];
    const float* W1 = (const float*)d_in[6];
    const float* b1 = (const float*)d_in[7];
    const float* W2 = (const float*)d_in[8];
    const float* b2 = (const float*)d_in[9];
    const float* W3 = (const float*)d_in[10];
    const float* b3 = (const float*)d_in[11];
    float* out = (float*)d_out;

    if (ws_size >= WS_NEED) {
        unsigned char* ws = (unsigned char*)d_ws;
        hipLaunchKernelGGL(cov_kernel, dim3(NV / 16), dim3(256), 0, stream,
                           coords, distsq, feats, nidx, ws);
        hipLaunchKernelGGL(mlp5b_kernel, dim3(GRID_MLP), dim3(256), 0, stream,
                           ws, W0, b0, W1, b1, W2, b2, W3, b3, out);
    } else {
        hipLaunchKernelGGL(fused_pca_mlp, dim3(NV / 16), dim3(256), 0, stream,
                           coords, distsq, feats, nidx,
                           W0, b0, W1, b1, W2, b2, W3, b3, out);
    }
}